// Round 1
// baseline (1022.378 us; speedup 1.0000x reference)
//
#include <hip/hip_runtime.h>
#include <cstdint>
#include <cstddef>

#define CE_B 4096
#define CE_C 50257

__device__ __forceinline__ void online_upd(float x, float& m, float& s) {
    if (x > m) {
        s = s * __expf(m - x) + 1.0f;
        m = x;
    } else {
        s += __expf(x - m);
    }
}

__device__ __forceinline__ void combine(float& m, float& s, float mo, float so) {
    float mn = fmaxf(m, mo);
    s = s * __expf(m - mn) + so * __expf(mo - mn);
    m = mn;
}

__global__ __launch_bounds__(256) void ce_row_kernel(const float* __restrict__ pred,
                                                     const int* __restrict__ target,
                                                     float* __restrict__ row_loss) {
    const int b = blockIdx.x;
    const int tid = threadIdx.x;
    const float* __restrict__ row = pred + (size_t)b * CE_C;

    float m = -INFINITY;
    float s = 0.0f;

    // Peel scalar head until 16B-aligned (row offset mod 16 varies since C is odd)
    const uintptr_t addr = (uintptr_t)row;
    const int mis = (int)((addr >> 2) & 3);       // fp32 elements past last 16B boundary
    const int head = (4 - mis) & 3;               // scalar elements before aligned body

    if (tid < head) {
        online_upd(row[tid], m, s);
    }

    const int n4 = (CE_C - head) >> 2;            // aligned float4 count (~12564)
    const float4* __restrict__ row4 = (const float4*)(row + head);
    for (int i = tid; i < n4; i += 256) {
        float4 v = row4[i];
        online_upd(v.x, m, s);
        online_upd(v.y, m, s);
        online_upd(v.z, m, s);
        online_upd(v.w, m, s);
    }

    const int tail_start = head + (n4 << 2);
    for (int i = tail_start + tid; i < CE_C; i += 256) {
        online_upd(row[i], m, s);
    }

    // Wave-64 butterfly reduce of (m, s)
    #pragma unroll
    for (int off = 32; off > 0; off >>= 1) {
        float mo = __shfl_xor(m, off, 64);
        float so = __shfl_xor(s, off, 64);
        combine(m, s, mo, so);
    }

    // Cross-wave (4 waves) via LDS
    __shared__ float sm[4];
    __shared__ float ss[4];
    if ((tid & 63) == 0) {
        sm[tid >> 6] = m;
        ss[tid >> 6] = s;
    }
    __syncthreads();

    if (tid == 0) {
        float M = sm[0], S = ss[0];
        #pragma unroll
        for (int w = 1; w < 4; ++w) combine(M, S, sm[w], ss[w]);
        float lse = M + __logf(S);
        float tv = row[target[b]];
        row_loss[b] = lse - tv;
    }
}

__global__ __launch_bounds__(256) void ce_reduce_kernel(const float* __restrict__ row_loss,
                                                        float* __restrict__ out) {
    const int tid = threadIdx.x;
    float s = 0.0f;
    for (int i = tid; i < CE_B; i += 256) s += row_loss[i];

    #pragma unroll
    for (int off = 32; off > 0; off >>= 1) s += __shfl_xor(s, off, 64);

    __shared__ float ws[4];
    if ((tid & 63) == 0) ws[tid >> 6] = s;
    __syncthreads();

    if (tid == 0) {
        float total = ws[0] + ws[1] + ws[2] + ws[3];
        out[0] = total / (float)CE_B;
    }
}

extern "C" void kernel_launch(void* const* d_in, const int* in_sizes, int n_in,
                              void* d_out, int out_size, void* d_ws, size_t ws_size,
                              hipStream_t stream) {
    const float* pred = (const float*)d_in[0];
    const int* target = (const int*)d_in[1];
    float* out = (float*)d_out;
    float* row_loss = (float*)d_ws;   // 4096 floats = 16 KB scratch

    ce_row_kernel<<<CE_B, 256, 0, stream>>>(pred, target, row_loss);
    ce_reduce_kernel<<<1, 256, 0, stream>>>(row_loss, out);
}

// Round 2
// 1020.960 us; speedup vs baseline: 1.0014x; 1.0014x over previous
//
#include <hip/hip_runtime.h>
#include <cstdint>
#include <cstddef>

#define CE_B 4096
#define CE_C 50257

// Branchless single-element online update (head/tail only)
__device__ __forceinline__ void upd1(float x, float& m, float& s) {
    float nm = fmaxf(m, x);
    s = s * __expf(m - nm) + __expf(x - nm);
    m = nm;
}

// Branchless float4 chunk update: 4 independent exps + one combine.
// Straight-line body lets the compiler software-pipeline the global loads.
__device__ __forceinline__ void chunk4(float4 v, float& m, float& s) {
    float lm = fmaxf(fmaxf(v.x, v.y), fmaxf(v.z, v.w));
    float e = __expf(v.x - lm) + __expf(v.y - lm)
            + __expf(v.z - lm) + __expf(v.w - lm);
    float nm = fmaxf(m, lm);
    // m == -inf initially: exp(-inf - nm) = 0, handled correctly by v_exp_f32
    s = s * __expf(m - nm) + e * __expf(lm - nm);
    m = nm;
}

__device__ __forceinline__ void combine(float& m, float& s, float mo, float so) {
    float mn = fmaxf(m, mo);
    s = s * __expf(m - mn) + so * __expf(mo - mn);
    m = mn;
}

__global__ __launch_bounds__(256) void ce_row_kernel(const float* __restrict__ pred,
                                                     const int* __restrict__ target,
                                                     float* __restrict__ row_loss) {
    const int b = blockIdx.x;
    const int tid = threadIdx.x;
    const float* __restrict__ row = pred + (size_t)b * CE_C;

    // Two independent accumulator pairs to shorten the carried dependency chain
    float m0 = -INFINITY, s0 = 0.0f;
    float m1 = -INFINITY, s1 = 0.0f;

    // Peel scalar head until 16B alignment (row offset mod 16 varies: C is odd)
    const uintptr_t addr = (uintptr_t)row;
    const int mis = (int)((addr >> 2) & 3);
    const int head = (4 - mis) & 3;

    if (tid < head) {
        upd1(row[tid], m0, s0);
    }

    const int n4 = (CE_C - head) >> 2;   // ~12564 aligned float4s
    const float4* __restrict__ row4 = (const float4*)(row + head);

    // 2x unrolled main loop: two independent loads in flight, two acc pairs
    int i = tid;
    for (; i + 256 < n4; i += 512) {
        float4 a = row4[i];
        float4 c = row4[i + 256];
        chunk4(a, m0, s0);
        chunk4(c, m1, s1);
    }
    for (; i < n4; i += 256) {
        chunk4(row4[i], m0, s0);
    }

    // Scalar tail
    const int tail_start = head + (n4 << 2);
    for (int t = tail_start + tid; t < CE_C; t += 256) {
        upd1(row[t], m0, s0);
    }

    // Merge the two accumulator pairs
    combine(m0, s0, m1, s1);

    // Wave-64 butterfly reduce
    #pragma unroll
    for (int off = 32; off > 0; off >>= 1) {
        float mo = __shfl_xor(m0, off, 64);
        float so = __shfl_xor(s0, off, 64);
        combine(m0, s0, mo, so);
    }

    // Cross-wave (4 waves) via LDS
    __shared__ float sm[4];
    __shared__ float ss[4];
    if ((tid & 63) == 0) {
        sm[tid >> 6] = m0;
        ss[tid >> 6] = s0;
    }
    __syncthreads();

    if (tid == 0) {
        float M = sm[0], S = ss[0];
        #pragma unroll
        for (int w = 1; w < 4; ++w) combine(M, S, sm[w], ss[w]);
        float lse = M + __logf(S);
        float tv = row[target[b]];
        row_loss[b] = lse - tv;
    }
}

__global__ __launch_bounds__(256) void ce_reduce_kernel(const float* __restrict__ row_loss,
                                                        float* __restrict__ out) {
    const int tid = threadIdx.x;
    float s = 0.0f;
    for (int i = tid; i < CE_B; i += 256) s += row_loss[i];

    #pragma unroll
    for (int off = 32; off > 0; off >>= 1) s += __shfl_xor(s, off, 64);

    __shared__ float ws[4];
    if ((tid & 63) == 0) ws[tid >> 6] = s;
    __syncthreads();

    if (tid == 0) {
        out[0] = (ws[0] + ws[1] + ws[2] + ws[3]) / (float)CE_B;
    }
}

extern "C" void kernel_launch(void* const* d_in, const int* in_sizes, int n_in,
                              void* d_out, int out_size, void* d_ws, size_t ws_size,
                              hipStream_t stream) {
    const float* pred = (const float*)d_in[0];
    const int* target = (const int*)d_in[1];
    float* out = (float*)d_out;
    float* row_loss = (float*)d_ws;   // 16 KB of scratch

    ce_row_kernel<<<CE_B, 256, 0, stream>>>(pred, target, row_loss);
    ce_reduce_kernel<<<1, 256, 0, stream>>>(row_loss, out);
}